// Round 8
// baseline (30.443 us; speedup 1.0000x reference)
//
#include <hip/hip_runtime.h>
#include <math.h>

#define PI_F    3.14159265358979323846f
#define TWO_PI  6.28318530717958647692f
#define HALF_PI 1.57079632679489661923f

__device__ __forceinline__ float frcp(float x)  { return __builtin_amdgcn_rcpf(x); }
__device__ __forceinline__ float frsq(float x)  { return __builtin_amdgcn_rsqf(x); }
__device__ __forceinline__ float fsqrt(float x) { return __builtin_amdgcn_sqrtf(x); }

// async global->LDS, 16B per lane: lds dest = uniform base + lane*16
__device__ __forceinline__ void glds16(const void* g, void* l) {
    __builtin_amdgcn_global_load_lds(
        (const __attribute__((address_space(1))) void*)g,
        (__attribute__((address_space(3))) void*)l, 16, 0, 0);
}

// atan2(y,x) mapped to [0, 2pi). A&S 4.4.49 poly, |err| <= 1e-5 rad.
__device__ __forceinline__ float fast_atan2_2pi(float y, float x) {
    float ax = fabsf(x), ay = fabsf(y);
    float mx = fmaxf(ax, ay), mn = fminf(ax, ay);
    float a  = (mx > 0.0f) ? mn * frcp(mx) : 0.0f;
    float s  = a * a;
    float r  = fmaf(s, fmaf(s, fmaf(s, fmaf(s, 0.0208351f, -0.085133f),
                                    0.180141f), -0.3302995f), 0.9998660f) * a;
    if (ay > ax) r = HALF_PI - r;
    if (x < 0.0f) r = PI_F - r;
    return (y < 0.0f) ? (TWO_PI - r) : r;
}

struct RotPW { float x0, x1, x2, y0, y1, y2; float4 pw; };

// Four items per wave (16-lane group per item, 4 comps/lane, K=64).
// The 88 MB cond w-stream is staged one quad AHEAD via async
// global_load_lds into wave-private double-buffered LDS, so HBM reads are
// continuously in flight (latency-decoupled). rot+pw prefetched in VGPRs
// one pass ahead. Counted s_waitcnt vmcnt(4): the 4 newest outstanding ops
// are exactly the next-quad stagings; all older ops drain.
__global__ __launch_bounds__(448)
void mobius_fwd(const float* __restrict__ rot,
                const float* __restrict__ cond,
                const void* __restrict__ perm,
                float* __restrict__ out,
                int B, int N)
{
    const int wave = threadIdx.x >> 6;
    const int lane = threadIdx.x & 63;
    const int sub  = lane >> 4;      // which of 4 items in the wave
    const int j    = lane & 15;      // 16-lane slot within item
    const int nwav = blockDim.x >> 6;   // 7

    const int b0     = blockIdx.x * 4;
    const int nb     = min(4, B - b0);
    const int nit    = N * nb;              // 84 when full
    const int nquads = (nit + 3) >> 2;      // 21 when full

    // permute: accept int32 or int64 delivery.
    const int* pi = (const int*)perm;
    int p0 = pi[0], p1 = pi[1], p2 = pi[2];
    bool pok = ((unsigned)p0 < 3u) && ((unsigned)p1 < 3u) && ((unsigned)p2 < 3u)
               && (p0 != p1) && (p0 != p2) && (p1 != p2);
    if (!pok) {
        const long long* pl = (const long long*)perm;
        p0 = (int)pl[0]; p1 = (int)pl[1]; p2 = (int)pl[2];
    }
    const int dd = p1 - p0;
    const bool swapc = (dd == 1 || dd == -2);

    // 7 waves x 2 buffers x 4 rows x 196 floats (192 data + 4 pad; pad sets
    // rows 4 banks apart so the 4 sub-groups' ds_reads interleave banks).
    __shared__ __align__(16) float cbuf[7][2][4][196];
    __shared__ float s_ldj[128];

    const size_t base_item = (size_t)b0 * N;

    auto stage = [&](int par, int qq) {
        if (lane < 48) {
            #pragma unroll
            for (int s = 0; s < 4; ++s) {
                int iv = min(4 * qq + s, nit - 1);
                const float* g = cond + (base_item + iv) * 256 + 64 + 4 * lane;
                glds16(g, &cbuf[wave][par][s][0]);
            }
        }
    };
    auto loadrp = [&](RotPW& d, int qq) {
        int iv = min(4 * qq + sub, nit - 1);
        const float* R = rot + (base_item + iv) * 9;
        d.x0 = R[p0]; d.x1 = R[3 + p0]; d.x2 = R[6 + p0];
        d.y0 = R[p1]; d.y1 = R[3 + p1]; d.y2 = R[6 + p1];
        d.pw = *(const float4*)(cond + (base_item + iv) * 256 + 4 * j);
    };

    RotPW cur{}, nxt{};
    stage(0, wave);            // prologue: stage my first quad
    loadrp(cur, wave);

    int par = 0;
    for (int q = wave; q < nquads; q += nwav, par ^= 1) {
        const int qn = q + nwav;
        const bool have_next = (qn < nquads);

        if (have_next) {
            stage(par ^ 1, qn);                           // 4 async stagings
            asm volatile("s_waitcnt vmcnt(4)" ::: "memory");  // keep only them in flight
        } else {
            asm volatile("s_waitcnt vmcnt(0)" ::: "memory");
        }
        __builtin_amdgcn_sched_barrier(0);

        // my 12 w-floats for this quad, from LDS
        const float* myl = &cbuf[wave][par][sub][12 * j];
        float4 fa = *(const float4*)(myl);
        float4 fb = *(const float4*)(myl + 4);
        float4 fc = *(const float4*)(myl + 8);

        if (have_next) loadrp(nxt, qn);   // VGPR prefetch (waited at next use)

        const int  i0    = 4 * q + sub;
        const bool valid = (i0 < nit);
        const size_t item = base_item + (valid ? i0 : 0);

        const float x0 = cur.x0, x1 = cur.x1, x2 = cur.x2;
        const float y0 = cur.y0, y1 = cur.y1, y2 = cur.y2;

        // per-item scalars
        float xn2    = x0 * x0 + x1 * x1 + x2 * x2;
        float inv_xn = frsq(xn2);
        float xn     = xn2 * inv_xn;
        float xy     = x0 * y0 + x1 * y1 + x2 * y2;
        float yn2    = y0 * y0 + y1 * y1 + y2 * y2;
        float negA   = yn2 - 2.0f;

        // v = normalize(x cross y)
        float cv0 = x1 * y2 - x2 * y1;
        float cv1 = x2 * y0 - x0 * y2;
        float cv2 = x0 * y1 - x1 * y0;
        float inv_cn = frsq(cv0 * cv0 + cv1 * cv1 + cv2 * cv2);
        float v0 = cv0 * inv_cn, v1 = cv1 * inv_cn, v2 = cv2 * inv_cn;

        float PW[4] = {cur.pw.x, cur.pw.y, cur.pw.z, cur.pw.w};
        float W0[4] = {fa.x, fa.w, fb.z, fc.y};
        float W1[4] = {fa.y, fb.x, fb.w, fc.z};
        float W2[4] = {fa.z, fb.y, fc.x, fc.w};

        float pp = 0.0f, pa = 0.0f, pd = 0.0f;
        #pragma unroll
        for (int cc = 0; cc < 4; ++cc) {
            float w0 = W0[cc], w1 = W1[cc], w2 = W2[cc];
            float yw  = y0 * w0 + y1 * w1 + y2 * w2;
            float wp2 = w0 * w0 + w1 * w1 + w2 * w2;
            float xwp = x0 * w0 + x1 * w1 + x2 * w2;
            float vwp = v0 * w0 + v1 * w1 + v2 * w2;
            float qn2 = fmaxf(fmaf(yw * yw, negA, wp2), 0.0f);  // ||proj w||^2
            float sc  = 0.7f * frcp(1.0f + fsqrt(qn2));
            float wn2 = (sc * sc) * qn2;
            float xw  = sc * fmaf(-xy, yw, xwp);            // x . w
            float zwn2 = fmaf(-2.0f, xw, xn2 + wn2);        // ||x-w||^2
            float c   = (1.0f - wn2) * frcp(zwn2);
            float cp1 = c + 1.0f;
            float hv  = -(cp1 * (sc * vwp));                // h.v
            float hr  = fmaf(cp1, xw * inv_xn, -(c * xn));  // h.r
            float ang = fast_atan2_2pi(hv, hr);
            float p   = __logf(1.0f + __expf(PW[cc]));      // softplus
            pp += p; pa = fmaf(p, ang, pa); pd = fmaf(p, c, pd);
        }

        // butterfly within each 16-lane group; sums land in ALL lanes
        #pragma unroll
        for (int off = 8; off >= 1; off >>= 1) {
            pp += __shfl_xor(pp, off, 64);
            pa += __shfl_xor(pa, off, 64);
            pd += __shfl_xor(pd, off, 64);
        }

        float ip   = frcp(pp);
        float angT = pa * ip;
        float ldj  = __logf(pd * ip);

        float sa, ca;
        __sincosf(angT, &sa, &ca);
        float r0 = -x0 * inv_xn, r1 = -x1 * inv_xn, r2 = -x2 * inv_xn;
        float t0 = fmaf(r0, ca, v0 * sa);
        float t1 = fmaf(r1, ca, v1 * sa);
        float t2 = fmaf(r2, ca, v2 * sa);

        float u0, u1, u2;
        if (swapc) {               // tz = cross(tx, y)
            u0 = t1 * y2 - t2 * y1;
            u1 = t2 * y0 - t0 * y2;
            u2 = t0 * y1 - t1 * y0;
        } else {                   // tz = cross(y, tx)
            u0 = y1 * t2 - y2 * t1;
            u1 = y2 * t0 - y0 * t2;
            u2 = y0 * t1 - y1 * t0;
        }
        float iun = frsq(u0 * u0 + u1 * u1 + u2 * u2);
        u0 *= iun; u1 *= iun; u2 *= iun;

        if (valid) {
            if (j < 9) {
                int row = (j >= 6) ? 2 : (j >= 3) ? 1 : 0;
                int cp  = j - 3 * row;
                float tr = (row == 0) ? t0 : (row == 1) ? t1 : t2;
                float yr = (row == 0) ? y0 : (row == 1) ? y1 : y2;
                float ur = (row == 0) ? u0 : (row == 1) ? u1 : u2;
                float val = (cp == p0) ? tr : (cp == p1) ? yr : ur;
                out[item * 9 + j] = val;
            }
            if (j == 0) s_ldj[i0] = ldj;
        }

        cur = nxt;
    }

    __syncthreads();
    if (threadIdx.x < nb) {
        float acc = 0.0f;
        for (int n = 0; n < N; ++n) acc += s_ldj[threadIdx.x * N + n];
        out[(size_t)B * N * 9 + b0 + threadIdx.x] = acc;
    }
}

extern "C" void kernel_launch(void* const* d_in, const int* in_sizes, int n_in,
                              void* d_out, int out_size, void* d_ws, size_t ws_size,
                              hipStream_t stream) {
    const float* rot  = (const float*)d_in[0];
    const float* cond = (const float*)d_in[1];
    const void*  perm = d_in[2];
    float* out = (float*)d_out;

    int items = in_sizes[0] / 9;           // B*N
    int B = out_size - items * 9;          // out = items*9 trot + B ldj
    int N = items / B;

    int grid = (B + 3) / 4;
    mobius_fwd<<<dim3(grid), dim3(448), 0, stream>>>(rot, cond, perm, out, B, N);
}

// Round 10
// 30.098 us; speedup vs baseline: 1.0115x; 1.0115x over previous
//
#include <hip/hip_runtime.h>
#include <math.h>

#define PI_F    3.14159265358979323846f
#define TWO_PI  6.28318530717958647692f
#define HALF_PI 1.57079632679489661923f

__device__ __forceinline__ float frcp(float x)  { return __builtin_amdgcn_rcpf(x); }
__device__ __forceinline__ float frsq(float x)  { return __builtin_amdgcn_rsqf(x); }
__device__ __forceinline__ float fsqrt(float x) { return __builtin_amdgcn_sqrtf(x); }

// async global->LDS, 16B per lane (HW-verified width): lane l writes
// lds_base + l*16. 48 lanes cover one 768B w-block.
__device__ __forceinline__ void glds16(const void* g, void* l) {
    __builtin_amdgcn_global_load_lds(
        (const __attribute__((address_space(1))) void*)g,
        (__attribute__((address_space(3))) void*)l, 16, 0, 0);
}

// atan2(y,x) mapped to [0, 2pi). A&S 4.4.49 poly, |err| <= 1e-5 rad.
__device__ __forceinline__ float fast_atan2_2pi(float y, float x) {
    float ax = fabsf(x), ay = fabsf(y);
    float mx = fmaxf(ax, ay), mn = fminf(ax, ay);
    float a  = (mx > 0.0f) ? mn * frcp(mx) : 0.0f;
    float s  = a * a;
    float r  = fmaf(s, fmaf(s, fmaf(s, fmaf(s, 0.0208351f, -0.085133f),
                                    0.180141f), -0.3302995f), 0.9998660f) * a;
    if (ay > ax) r = HALF_PI - r;
    if (x < 0.0f) r = PI_F - r;
    return (y < 0.0f) ? (TWO_PI - r) : r;
}

// Four items per wave (16-lane group per item, 4 comps/lane, K=64).
// w-part of each cond row (768B) staged ONE pass ahead via 16B async
// global_load_lds (lanes 0..47) into wave-private double-buffered LDS.
// pw+rot are direct VGPR loads issued BEFORE the staging (compiler fence
// pins the order), so `s_waitcnt vmcnt(4)` drains them AND the current
// buffer's stagings while keeping exactly the 4 next-pass stagings in
// flight across the whole compute phase.
__global__ __launch_bounds__(448)
void mobius_fwd(const float* __restrict__ rot,
                const float* __restrict__ cond,
                const void* __restrict__ perm,
                float* __restrict__ out,
                int B, int N)
{
    const int wave = threadIdx.x >> 6;
    const int lane = threadIdx.x & 63;
    const int sub  = lane >> 4;      // which of 4 items in the wave
    const int j    = lane & 15;      // 16-lane slot within item
    const int nwav = blockDim.x >> 6;   // 7

    const int b0     = blockIdx.x * 4;
    const int nb     = min(4, B - b0);
    const int nit    = N * nb;              // 84 when full
    const int nquads = (nit + 3) >> 2;      // 21 when full

    // permute: accept int32 or int64 delivery.
    const int* pi = (const int*)perm;
    int p0 = pi[0], p1 = pi[1], p2 = pi[2];
    bool pok = ((unsigned)p0 < 3u) && ((unsigned)p1 < 3u) && ((unsigned)p2 < 3u)
               && (p0 != p1) && (p0 != p2) && (p1 != p2);
    if (!pok) {
        const long long* pl = (const long long*)perm;
        p0 = (int)pl[0]; p1 = (int)pl[1]; p2 = (int)pl[2];
    }
    const int dd = p1 - p0;
    const bool swapc = (dd == 1 || dd == -2);

    // 7 waves x 2 buffers x 4 rows x (192 data + 4 pad) floats = 43.9 KB
    __shared__ __align__(16) float cbuf[7][2][4][196];
    __shared__ float s_ldj[128];

    const size_t base_item = (size_t)b0 * N;

    auto stage = [&](int par, int qq) {
        if (lane < 48) {
            #pragma unroll
            for (int s = 0; s < 4; ++s) {
                int iv = min(4 * qq + s, nit - 1);
                const float* g = cond + (base_item + iv) * 256 + 64 + 4 * lane;
                glds16(g, &cbuf[wave][par][s][0]);
            }
        }
    };

    stage(0, wave);            // prologue: stage my first quad's w-blocks

    int par = 0;
    for (int q = wave; q < nquads; q += nwav, par ^= 1) {
        const int  i0    = 4 * q + sub;
        const bool valid = (i0 < nit);
        const size_t item = base_item + (valid ? i0 : 0);

        // direct VGPR loads for THIS pass — must be issued before the
        // staging so the counted vmcnt below drains them.
        const float* C = cond + item * 256;
        float4 pw4 = *(const float4*)(C + 4 * j);
        const float* R = rot + item * 9;
        float x0 = R[p0], x1 = R[3 + p0], x2 = R[6 + p0];
        float y0 = R[p1], y1 = R[3 + p1], y2 = R[6 + p1];

        asm volatile("" ::: "memory");   // pin load-vs-stage program order

        const int qn = q + nwav;
        const bool have_next = (qn < nquads);
        if (have_next) {
            stage(par ^ 1, qn);                               // 4 async stagings
            asm volatile("s_waitcnt vmcnt(4)" ::: "memory");  // keep only them
        } else {
            asm volatile("s_waitcnt vmcnt(0)" ::: "memory");
        }

        // my 12 w-floats for this quad, from LDS (current buffer)
        const float* myl = &cbuf[wave][par][sub][12 * j];
        float4 fa = *(const float4*)(myl);
        float4 fb = *(const float4*)(myl + 4);
        float4 fc = *(const float4*)(myl + 8);

        // per-item scalars
        float xn2    = x0 * x0 + x1 * x1 + x2 * x2;
        float inv_xn = frsq(xn2);
        float xn     = xn2 * inv_xn;
        float xy     = x0 * y0 + x1 * y1 + x2 * y2;
        float yn2    = y0 * y0 + y1 * y1 + y2 * y2;
        float negA   = yn2 - 2.0f;

        // v = normalize(x cross y)
        float cv0 = x1 * y2 - x2 * y1;
        float cv1 = x2 * y0 - x0 * y2;
        float cv2 = x0 * y1 - x1 * y0;
        float inv_cn = frsq(cv0 * cv0 + cv1 * cv1 + cv2 * cv2);
        float v0 = cv0 * inv_cn, v1 = cv1 * inv_cn, v2 = cv2 * inv_cn;

        float PW[4] = {pw4.x, pw4.y, pw4.z, pw4.w};
        float W0[4] = {fa.x, fa.w, fb.z, fc.y};
        float W1[4] = {fa.y, fb.x, fb.w, fc.z};
        float W2[4] = {fa.z, fb.y, fc.x, fc.w};

        float pp = 0.0f, pa = 0.0f, pd = 0.0f;
        #pragma unroll
        for (int cc = 0; cc < 4; ++cc) {
            float w0 = W0[cc], w1 = W1[cc], w2 = W2[cc];
            float yw  = y0 * w0 + y1 * w1 + y2 * w2;
            float wp2 = w0 * w0 + w1 * w1 + w2 * w2;
            float xwp = x0 * w0 + x1 * w1 + x2 * w2;
            float vwp = v0 * w0 + v1 * w1 + v2 * w2;
            float qn2 = fmaxf(fmaf(yw * yw, negA, wp2), 0.0f);  // ||proj w||^2
            float sc  = 0.7f * frcp(1.0f + fsqrt(qn2));
            float wn2 = (sc * sc) * qn2;
            float xw  = sc * fmaf(-xy, yw, xwp);            // x . w
            float zwn2 = fmaf(-2.0f, xw, xn2 + wn2);        // ||x-w||^2
            float c   = (1.0f - wn2) * frcp(zwn2);
            float cp1 = c + 1.0f;
            float hv  = -(cp1 * (sc * vwp));                // h.v
            float hr  = fmaf(cp1, xw * inv_xn, -(c * xn));  // h.r
            float ang = fast_atan2_2pi(hv, hr);
            float p   = __logf(1.0f + __expf(PW[cc]));      // softplus
            pp += p; pa = fmaf(p, ang, pa); pd = fmaf(p, c, pd);
        }

        // butterfly within each 16-lane group
        #pragma unroll
        for (int off = 8; off >= 1; off >>= 1) {
            pp += __shfl_xor(pp, off, 64);
            pa += __shfl_xor(pa, off, 64);
            pd += __shfl_xor(pd, off, 64);
        }

        if (j == 0 && valid) {
            float ip   = frcp(pp);
            float angT = pa * ip;
            float ldj  = __logf(pd * ip);

            float sa, ca;
            __sincosf(angT, &sa, &ca);
            float r0 = -x0 * inv_xn, r1 = -x1 * inv_xn, r2 = -x2 * inv_xn;
            float t0 = fmaf(r0, ca, v0 * sa);
            float t1 = fmaf(r1, ca, v1 * sa);
            float t2 = fmaf(r2, ca, v2 * sa);

            float u0, u1, u2;
            if (swapc) {               // tz = cross(tx, y)
                u0 = t1 * y2 - t2 * y1;
                u1 = t2 * y0 - t0 * y2;
                u2 = t0 * y1 - t1 * y0;
            } else {                   // tz = cross(y, tx)
                u0 = y1 * t2 - y2 * t1;
                u1 = y2 * t0 - y0 * t2;
                u2 = y0 * t1 - y1 * t0;
            }
            float iun = frsq(u0 * u0 + u1 * u1 + u2 * u2);
            u0 *= iun; u1 *= iun; u2 *= iun;

            float* T = out + item * 9;
            T[p0] = t0; T[3 + p0] = t1; T[6 + p0] = t2;
            T[p1] = y0; T[3 + p1] = y1; T[6 + p1] = y2;
            T[p2] = u0; T[3 + p2] = u1; T[6 + p2] = u2;

            s_ldj[i0] = ldj;
        }
    }

    __syncthreads();
    if (threadIdx.x < nb) {
        float acc = 0.0f;
        for (int n = 0; n < N; ++n) acc += s_ldj[threadIdx.x * N + n];
        out[(size_t)B * N * 9 + b0 + threadIdx.x] = acc;
    }
}

extern "C" void kernel_launch(void* const* d_in, const int* in_sizes, int n_in,
                              void* d_out, int out_size, void* d_ws, size_t ws_size,
                              hipStream_t stream) {
    const float* rot  = (const float*)d_in[0];
    const float* cond = (const float*)d_in[1];
    const void*  perm = d_in[2];
    float* out = (float*)d_out;

    int items = in_sizes[0] / 9;           // B*N
    int B = out_size - items * 9;          // out = items*9 trot + B ldj
    int N = items / B;

    int grid = (B + 3) / 4;
    mobius_fwd<<<dim3(grid), dim3(448), 0, stream>>>(rot, cond, perm, out, B, N);
}

// Round 11
// 25.663 us; speedup vs baseline: 1.1862x; 1.1728x over previous
//
#include <hip/hip_runtime.h>
#include <math.h>

#define PI_F    3.14159265358979323846f
#define TWO_PI  6.28318530717958647692f
#define HALF_PI 1.57079632679489661923f

__device__ __forceinline__ float frcp(float x)  { return __builtin_amdgcn_rcpf(x); }
__device__ __forceinline__ float frsq(float x)  { return __builtin_amdgcn_rsqf(x); }
__device__ __forceinline__ float fsqrt(float x) { return __builtin_amdgcn_sqrtf(x); }

// atan2(y,x) mapped to [0, 2pi). A&S 4.4.49 poly, |err| <= 1e-5 rad.
__device__ __forceinline__ float fast_atan2_2pi(float y, float x) {
    float ax = fabsf(x), ay = fabsf(y);
    float mx = fmaxf(ax, ay), mn = fminf(ax, ay);
    float a  = (mx > 0.0f) ? mn * frcp(mx) : 0.0f;
    float s  = a * a;
    float r  = fmaf(s, fmaf(s, fmaf(s, fmaf(s, 0.0208351f, -0.085133f),
                                    0.180141f), -0.3302995f), 0.9998660f) * a;
    if (ay > ax) r = HALF_PI - r;
    if (x < 0.0f) r = PI_F - r;
    return (y < 0.0f) ? (TWO_PI - r) : r;
}

// EIGHT items per wave: 8-lane group per item; lane j (0..7) handles
// mixture components 8j..8j+7 (K=64). Direct global float4 loads (the
// repeatedly-validated fastest data path), dot-form per-component algebra.
// Block of 7 waves covers EIGHT batch rows (168 items = 21 octets) in
// exactly 3 passes per wave. Setup/reduction/epilogue per-item cost is
// half of the 4-item layout (wave-amortized); reduction is 3 butterfly
// steps. __launch_bounds__(448,4): VGPR <= 128 keeps both blocks/CU
// co-resident (grid 512 = 2 blocks/CU).
__global__ __launch_bounds__(448, 4)
void mobius_fwd(const float* __restrict__ rot,
                const float* __restrict__ cond,
                const void* __restrict__ perm,
                float* __restrict__ out,
                int B, int N)
{
    const int wave = threadIdx.x >> 6;
    const int lane = threadIdx.x & 63;
    const int sub  = lane >> 3;      // which of 8 items in the wave
    const int j    = lane & 7;       // 8-lane slot within item
    const int nwav = blockDim.x >> 6;   // 7

    const int b0   = blockIdx.x * 8;
    const int nb   = min(8, B - b0);
    const int nit  = N * nb;               // 168 when full
    const int noct = (nit + 7) >> 3;       // 21 when full

    // permute: accept int32 or int64 delivery.
    const int* pi = (const int*)perm;
    int p0 = pi[0], p1 = pi[1], p2 = pi[2];
    bool pok = ((unsigned)p0 < 3u) && ((unsigned)p1 < 3u) && ((unsigned)p2 < 3u)
               && (p0 != p1) && (p0 != p2) && (p1 != p2);
    if (!pok) {
        const long long* pl = (const long long*)perm;
        p0 = (int)pl[0]; p1 = (int)pl[1]; p2 = (int)pl[2];
    }
    const int dd = p1 - p0;
    const bool swapc = (dd == 1 || dd == -2);

    __shared__ float s_ldj[192];

    const size_t base_item = (size_t)b0 * N;

    for (int q = wave; q < noct; q += nwav) {
        const int  i0    = 8 * q + sub;
        const bool valid = (i0 < nit);
        const size_t item = base_item + (valid ? i0 : 0);

        // my 8 components: 32 floats via 8 aligned float4 loads
        const float* C = cond + item * 256;
        float4 pwa = *(const float4*)(C + 8 * j);
        float4 pwb = *(const float4*)(C + 8 * j + 4);
        const float* W = C + 64 + 24 * j;
        float4 f0 = ((const float4*)W)[0];
        float4 f1 = ((const float4*)W)[1];
        float4 f2 = ((const float4*)W)[2];
        float4 f3 = ((const float4*)W)[3];
        float4 f4 = ((const float4*)W)[4];
        float4 f5 = ((const float4*)W)[5];

        // rot columns p0 (x) and p1 (y), raw
        const float* R = rot + item * 9;
        float x0 = R[p0], x1 = R[3 + p0], x2 = R[6 + p0];
        float y0 = R[p1], y1 = R[3 + p1], y2 = R[6 + p1];

        // per-item scalars (computed lane-parallel for all 8 items)
        float xn2    = x0 * x0 + x1 * x1 + x2 * x2;
        float inv_xn = frsq(xn2);
        float xn     = xn2 * inv_xn;
        float xy     = x0 * y0 + x1 * y1 + x2 * y2;
        float yn2    = y0 * y0 + y1 * y1 + y2 * y2;
        float negA   = yn2 - 2.0f;

        // v = normalize(x cross y)
        float cv0 = x1 * y2 - x2 * y1;
        float cv1 = x2 * y0 - x0 * y2;
        float cv2 = x0 * y1 - x1 * y0;
        float inv_cn = frsq(cv0 * cv0 + cv1 * cv1 + cv2 * cv2);
        float v0 = cv0 * inv_cn, v1 = cv1 * inv_cn, v2 = cv2 * inv_cn;

        float PW[8] = {pwa.x, pwa.y, pwa.z, pwa.w, pwb.x, pwb.y, pwb.z, pwb.w};
        float W0[8] = {f0.x, f0.w, f1.z, f2.y, f3.x, f3.w, f4.z, f5.y};
        float W1[8] = {f0.y, f1.x, f1.w, f2.z, f3.y, f4.x, f4.w, f5.z};
        float W2[8] = {f0.z, f1.y, f2.x, f2.w, f3.z, f4.y, f5.x, f5.w};

        float pp = 0.0f, pa = 0.0f, pd = 0.0f;
        #pragma unroll
        for (int cc = 0; cc < 8; ++cc) {
            float w0 = W0[cc], w1 = W1[cc], w2 = W2[cc];
            float yw  = y0 * w0 + y1 * w1 + y2 * w2;
            float wp2 = w0 * w0 + w1 * w1 + w2 * w2;
            float xwp = x0 * w0 + x1 * w1 + x2 * w2;
            float vwp = v0 * w0 + v1 * w1 + v2 * w2;
            float qn2 = fmaxf(fmaf(yw * yw, negA, wp2), 0.0f);  // ||proj w||^2
            float sc  = 0.7f * frcp(1.0f + fsqrt(qn2));
            float wn2 = (sc * sc) * qn2;
            float xw  = sc * fmaf(-xy, yw, xwp);            // x . w
            float zwn2 = fmaf(-2.0f, xw, xn2 + wn2);        // ||x-w||^2
            float c   = (1.0f - wn2) * frcp(zwn2);
            float cp1 = c + 1.0f;
            float hv  = -(cp1 * (sc * vwp));                // h.v
            float hr  = fmaf(cp1, xw * inv_xn, -(c * xn));  // h.r
            float ang = fast_atan2_2pi(hv, hr);
            float p   = __logf(1.0f + __expf(PW[cc]));      // softplus
            pp += p; pa = fmaf(p, ang, pa); pd = fmaf(p, c, pd);
        }

        // butterfly within each 8-lane group (3 steps)
        #pragma unroll
        for (int off = 4; off >= 1; off >>= 1) {
            pp += __shfl_xor(pp, off, 64);
            pa += __shfl_xor(pa, off, 64);
            pd += __shfl_xor(pd, off, 64);
        }

        if (j == 0 && valid) {
            float ip   = frcp(pp);
            float angT = pa * ip;
            float ldj  = __logf(pd * ip);

            float sa, ca;
            __sincosf(angT, &sa, &ca);
            float r0 = -x0 * inv_xn, r1 = -x1 * inv_xn, r2 = -x2 * inv_xn;
            float t0 = fmaf(r0, ca, v0 * sa);
            float t1 = fmaf(r1, ca, v1 * sa);
            float t2 = fmaf(r2, ca, v2 * sa);

            float u0, u1, u2;
            if (swapc) {               // tz = cross(tx, y)
                u0 = t1 * y2 - t2 * y1;
                u1 = t2 * y0 - t0 * y2;
                u2 = t0 * y1 - t1 * y0;
            } else {                   // tz = cross(y, tx)
                u0 = y1 * t2 - y2 * t1;
                u1 = y2 * t0 - y0 * t2;
                u2 = y0 * t1 - y1 * t0;
            }
            float iun = frsq(u0 * u0 + u1 * u1 + u2 * u2);
            u0 *= iun; u1 *= iun; u2 *= iun;

            float* T = out + item * 9;
            T[p0] = t0; T[3 + p0] = t1; T[6 + p0] = t2;
            T[p1] = y0; T[3 + p1] = y1; T[6 + p1] = y2;
            T[p2] = u0; T[3 + p2] = u1; T[6 + p2] = u2;

            s_ldj[i0] = ldj;
        }
    }

    __syncthreads();
    if (threadIdx.x < nb) {
        float acc = 0.0f;
        for (int n = 0; n < N; ++n) acc += s_ldj[threadIdx.x * N + n];
        out[(size_t)B * N * 9 + b0 + threadIdx.x] = acc;
    }
}

extern "C" void kernel_launch(void* const* d_in, const int* in_sizes, int n_in,
                              void* d_out, int out_size, void* d_ws, size_t ws_size,
                              hipStream_t stream) {
    const float* rot  = (const float*)d_in[0];
    const float* cond = (const float*)d_in[1];
    const void*  perm = d_in[2];
    float* out = (float*)d_out;

    int items = in_sizes[0] / 9;           // B*N
    int B = out_size - items * 9;          // out = items*9 trot + B ldj
    int N = items / B;

    int grid = (B + 7) / 8;
    mobius_fwd<<<dim3(grid), dim3(448), 0, stream>>>(rot, cond, perm, out, B, N);
}